// Round 4
// baseline (145.060 us; speedup 1.0000x reference)
//
#include <hip/hip_runtime.h>
#include <stdint.h>

#define B_    16
#define CIN_  128
#define COUT_ 128
#define H_    64
#define W_    64
#define L_    4096
#define KK_   1152
#define PW_   66                 // padded image dim (halo 1 each side)

typedef unsigned short u16;
typedef __bf16 bf16x8 __attribute__((ext_vector_type(8)));
typedef float  floatx4 __attribute__((ext_vector_type(4)));
typedef uint32_t u32x4 __attribute__((ext_vector_type(4)));

typedef const __attribute__((address_space(1))) uint32_t* gptr_t;
typedef __attribute__((address_space(3))) uint32_t*       lptr_t;

__device__ __forceinline__ void async_copy16(const void* g, void* l) {
    // 64 lanes x 16 B = 1 KB; LDS dest = wave-uniform base + lane*16
    __builtin_amdgcn_global_load_lds((gptr_t)g, (lptr_t)l, 16, 0, 0);
}

__device__ __forceinline__ u16 f2bf(float f) {
    uint32_t u = __builtin_bit_cast(uint32_t, f);
    uint32_t r = u + 0x7FFFu + ((u >> 16) & 1u);   // round-to-nearest-even
    return (u16)(r >> 16);
}

// ---------------------------------------------------------------------------
// P1 fused: blockIdx.y < 16 : x [B][CIN][64][64] f32 -> xTp [B][66][66][CIN] bf16
//           blockIdx.y ==16 : mb[o][l] precompute + weight reorder wb2[k][o][c]
// ---------------------------------------------------------------------------
__global__ void lmc_pre_kernel(const float* __restrict__ x, u16* __restrict__ xTp,
                               const float* __restrict__ mask, const float* __restrict__ mw,
                               const float* __restrict__ bias, const float* __restrict__ w,
                               float* __restrict__ mb, u16* __restrict__ wb2) {
    __shared__ u16 tile[64][CIN_ + 8];
    const int tid = threadIdx.x;

    if (blockIdx.y == 16) {
        // ---- prep branch: 64 blocks
        const int bid = blockIdx.x;
        // weight reorder: 64 * 2304 = 147456 elements exact
        const int base = bid * 2304;
        #pragma unroll
        for (int i = 0; i < 9; ++i) {
            const int e = base + i * 256 + tid;
            const int k = e >> 14;
            const int rem = e & 16383;
            const int o = rem >> 7, c = rem & 127;
            wb2[e] = f2bf(w[(size_t)o * KK_ + c * 9 + k]);
        }
        // mb: two output channels per block
        #pragma unroll
        for (int oo = 0; oo < 2; ++oo) {
            const int o = bid * 2 + oo;
            float m[9];
            #pragma unroll
            for (int k = 0; k < 9; ++k) m[k] = mw[o * 9 + k];
            const float bs = bias[o];
            for (int l = tid; l < L_; l += 256) {
                float s = bs;
                #pragma unroll
                for (int k = 0; k < 9; ++k) s += m[k] * mask[k * L_ + l];
                mb[o * L_ + l] = s;
            }
        }
        return;
    }

    // ---- transpose branch
    const int b = blockIdx.y;
    const int y = blockIdx.x;        // 0..63
    {
        const int c  = tid >> 1;
        const int x0 = (tid & 1) * 32;
        const float* src = x + ((size_t)b * CIN_ + c) * L_ + y * 64 + x0;
        #pragma unroll
        for (int j = 0; j < 32; j += 4) {
            float4 v = *reinterpret_cast<const float4*>(src + j);
            tile[x0 + j + 0][c] = f2bf(v.x);
            tile[x0 + j + 1][c] = f2bf(v.y);
            tile[x0 + j + 2][c] = f2bf(v.z);
            tile[x0 + j + 3][c] = f2bf(v.w);
        }
    }
    __syncthreads();

    u16* dstrow = xTp + ((size_t)(b * PW_ + (y + 1)) * PW_) * CIN_;  // pixel (y+1, 0)
    {
        const int xx   = tid >> 2;
        const int cseg = (tid & 3) * 32;
        u16* dst = dstrow + (size_t)(xx + 1) * CIN_ + cseg;
        #pragma unroll
        for (int i = 0; i < 32; i += 8) {
            *reinterpret_cast<uint4*>(dst + i) =
                *reinterpret_cast<const uint4*>(&tile[xx][cseg + i]);
        }
    }
    const uint4 z = {0u, 0u, 0u, 0u};
    if (tid < 32) {   // x-halo pixels (y+1, 0) and (y+1, 65)
        const int pix = (tid >> 4) ? 65 : 0;
        *reinterpret_cast<uint4*>(dstrow + (size_t)pix * CIN_ + (tid & 15) * 8) = z;
    }
    if (y == 0 || y == 63) {   // y-halo rows 0 / 65 (full padded width)
        u16* brow = xTp + ((size_t)(b * PW_ + (y == 0 ? 0 : 65)) * PW_) * CIN_;
        for (int i = tid; i < (PW_ * CIN_) / 8; i += 256)
            reinterpret_cast<uint4*>(brow)[i] = z;
    }
}

// ---------------------------------------------------------------------------
// Main GEMM, barrier-free K-loop:
//   - Bwin: 4 padded rows x 64 interior cols x 128 ch bf16 = 64 KB LDS,
//     staged ONCE via global_load_lds (XOR-8 chunk swizzle on col). All 9 taps
//     read shifted windows from it (y via row offset, x via clamped col;
//     x-out-of-bounds folded into mask bits since padded cols are zero).
//   - A (weights) per tap streamed global->VGPR (32 KB slab, L1-resident).
//   - One __syncthreads total; MFMA/VMEM/LDS/VALU free-run, 2 blocks/CU.
// ---------------------------------------------------------------------------
__global__ __launch_bounds__(256, 2)
void lmc_gemm_kernel(const u16* __restrict__ xTp, const u16* __restrict__ wb2,
                     const float* __restrict__ mask, const float* __restrict__ mb,
                     float* __restrict__ out) {
    __shared__ u16 Bwin[4 * 64 * 128];     // 64 KB: [row][col][chunk swizzled]

    const int b    = blockIdx.y;
    const int tile = blockIdx.x;           // 0..31, image rows {2t, 2t+1}
    const int l0   = tile * 128;
    const int tid  = threadIdx.x;
    const int lane = tid & 63;
    const int wv   = tid >> 6;
    const int wm   = (wv >> 1) * 64;
    const int wn   = (wv & 1) * 64;
    const int lrow = lane & 15;
    const int quad = lane >> 4;

    // ---- stage Bwin once: padded rows 2*tile .. 2*tile+3, interior cols 1..64
    {
        const char* srcrow = (const char*)xTp
            + ((size_t)((b * PW_) + tile * 2 + wv) * PW_ + 1) * 256;
        char* dst = (char*)Bwin + wv * 16384;   // wave wv stages row wv
        const int cl = lane >> 4;               // 0..3
        #pragma unroll
        for (int seg = 0; seg < 16; ++seg) {
            const int col = seg * 4 + cl;
            const int ch  = (lane & 15) ^ (col & 7);
            async_copy16(srcrow + col * 256 + ch * 16, dst + seg * 1024);
        }
    }

    // ---- pack 36 bits: bit(k,j) = mask[k][l] != 0  AND  x+dx in [0,64)
    uint64_t bits = 0;
    #pragma unroll
    for (int j = 0; j < 4; ++j) {
        const int xl  = j * 16 + lrow;           // 0..63 (wn is 0 or 64)
        const int l_g = l0 + wn + xl;
        #pragma unroll
        for (int k = 0; k < 9; ++k) {
            const int dx = k - (k / 3) * 3 - 1;
            const bool xok = (unsigned)(xl + dx) < 64u;
            if (xok && mask[k * L_ + l_g] != 0.0f) bits |= (1ull << (k * 4 + j));
        }
    }

    floatx4 acc[4][4];
    #pragma unroll
    for (int i = 0; i < 4; ++i)
        #pragma unroll
        for (int j = 0; j < 4; ++j)
            acc[i][j] = (floatx4){0.f, 0.f, 0.f, 0.f};

    int rowA[4];
    #pragma unroll
    for (int i = 0; i < 4; ++i) rowA[i] = (wm + i * 16 + lrow) * 256 + quad * 16;
    const int ywave = wn >> 6;                 // 0 or 1: wave's image row in tile
    const char* wb2_c = (const char*)wb2;
    const char* Bw = (const char*)Bwin;

    __syncthreads();   // Bwin ready; no more barriers

    for (int k = 0; k < 9; ++k) {
        const int dy = k / 3 - 1;
        const int dx = k - (k / 3) * 3 - 1;
        const char* Ak = wb2_c + k * 32768;
        const int rowbase = (ywave + 1 + dy) * 16384;   // Bwin row byte offset

        int baddr[4], c7[4];
        #pragma unroll
        for (int j = 0; j < 4; ++j) {
            int col = j * 16 + lrow + dx;
            col = min(max(col, 0), 63);        // clamp; OOB lanes masked by bits
            baddr[j] = rowbase + col * 256;
            c7[j] = col & 7;
        }
        uint32_t kp[4];
        #pragma unroll
        for (int j = 0; j < 4; ++j)
            kp[j] = 0u - (uint32_t)((bits >> (k * 4 + j)) & 1ull);

        #pragma unroll
        for (int ks = 0; ks < 4; ++ks) {
            bf16x8 af[4], bfr[4];
            #pragma unroll
            for (int i = 0; i < 4; ++i)        // global b128 loads (L1/L2)
                af[i] = *reinterpret_cast<const bf16x8*>(Ak + rowA[i] + ks * 64);
            #pragma unroll
            for (int j = 0; j < 4; ++j) {
                const int slot = ((ks * 4 + quad) ^ c7[j]) * 16;
                bf16x8 v = *reinterpret_cast<const bf16x8*>(Bw + baddr[j] + slot);
                u32x4 t = __builtin_bit_cast(u32x4, v);
                t &= kp[j];
                bfr[j] = __builtin_bit_cast(bf16x8, t);
            }
            #pragma unroll
            for (int i = 0; i < 4; ++i)
                #pragma unroll
                for (int j = 0; j < 4; ++j)
                    acc[i][j] = __builtin_amdgcn_mfma_f32_16x16x32_bf16(af[i], bfr[j], acc[i][j], 0, 0, 0);
        }
    }

    // ---- epilogue: C/D layout col = lane&15 (l), row = quad*4 + r (o)
    #pragma unroll
    for (int i = 0; i < 4; ++i) {
        #pragma unroll
        for (int j = 0; j < 4; ++j) {
            const int l = l0 + wn + j * 16 + lrow;
            #pragma unroll
            for (int r = 0; r < 4; ++r) {
                const int o = wm + i * 16 + quad * 4 + r;
                out[((size_t)b * COUT_ + o) * L_ + l] = acc[i][j][r] + mb[o * L_ + l];
            }
        }
    }
}

// ---------------------------------------------------------------------------
extern "C" void kernel_launch(void* const* d_in, const int* in_sizes, int n_in,
                              void* d_out, int out_size, void* d_ws, size_t ws_size,
                              hipStream_t stream) {
    const float* x      = (const float*)d_in[0];
    const float* mask   = (const float*)d_in[1];
    const float* weight = (const float*)d_in[2];
    const float* mw     = (const float*)d_in[3];
    const float* bias   = (const float*)d_in[4];
    float* out = (float*)d_out;

    char* ws = (char*)d_ws;
    u16*   xTp = (u16*)ws;                                  // 16*4356*128*2 = 17,842,176 B
    u16*   wb2 = (u16*)(ws + 17842176);                     // 294,912 B  [9][128][128] bf16
    float* mb  = (float*)(ws + 17842176 + 294912);          // 2,097,152 B [128][4096] f32

    lmc_pre_kernel<<<dim3(64, 17), 256, 0, stream>>>(x, xTp, mask, mw, bias, weight, mb, wb2);
    lmc_gemm_kernel<<<dim3(32, 16), 256, 0, stream>>>(xTp, wb2, mask, mb, out);
}